// Round 2
// baseline (332.638 us; speedup 1.0000x reference)
//
#include <hip/hip_runtime.h>

#define BATCH 65536
#define AR 16
#define UD 15
#define SEQ 1024
#define RDIM 17          // regressor dim: 16 y taps + const
#define CPB 256          // columns (timesteps) per block in kernel 2

// ---------------------------------------------------------------------------
// Kernel 1: compute Gamma[SEQ][17] in d_ws.
//   out[row][t] = sum_i r_row[i] * Gamma[t][i],  r_row = [y0..y15, c_row].
//   Gamma rows t<16 are identity (out copies y exactly, in fp32).
//   For t>=16: g_t = sum_j w_ar[j] * g_{t-16+j} + e16  (e16 = const channel).
// One wave, lanes 0..16 each own one regressor component; ring of 16 g-values
// in VGPRs with compile-time circular indexing (inner 16 unrolled).
// ---------------------------------------------------------------------------
__global__ __launch_bounds__(64) void gamma_kernel(
    const float* __restrict__ w, float* __restrict__ G)
{
    const int i = threadIdx.x;            // component id, active i < 17
    float w_ar[AR];
#pragma unroll
    for (int k = 0; k < AR; ++k) w_ar[k] = w[k];   // uniform -> SGPRs

    const float e16 = (i == 16) ? 1.0f : 0.0f;
    float ring[AR];
#pragma unroll
    for (int k = 0; k < AR; ++k) ring[k] = (i == k) ? 1.0f : 0.0f;

    // identity rows t = 0..15
    if (i < RDIM) {
#pragma unroll
        for (int t = 0; t < AR; ++t) G[t * RDIM + i] = (i == t) ? 1.0f : 0.0f;
    }

    for (int tb = 0; tb < (SEQ - AR) / AR; ++tb) {   // 63 outer iterations
#pragma unroll
        for (int s = 0; s < AR; ++s) {               // pred index j = tb*16+s
            float p0 = e16, p1 = 0.0f;
#pragma unroll
            for (int k = 0; k < 8; ++k)  p0 = fmaf(ring[(s + k) & 15], w_ar[k], p0);
#pragma unroll
            for (int k = 8; k < 16; ++k) p1 = fmaf(ring[(s + k) & 15], w_ar[k], p1);
            const float p = p0 + p1;
            ring[s & 15] = p;
            if (i < RDIM) G[(AR + tb * AR + s) * RDIM + i] = p;
        }
    }
}

// ---------------------------------------------------------------------------
// Kernel 2: out[row][t] = r_row . Gamma[t].  Pure streaming-write kernel.
// Grid: (BATCH/64) rowblocks x (SEQ/CPB) colblocks -> 4096 one-wave blocks
// = 4 waves/SIMD (latency hiding for store drains / LDS).
// Gamma addresses are block-uniform -> scalar (s_load) path; values feed
// per-lane FMAs. 32-column tiles staged in LDS [64][33] (conflict-free) and
// flushed transposed: each store instruction covers two 128B row segments.
// ---------------------------------------------------------------------------
__global__ __launch_bounds__(64) void arx_gemm_kernel(
    const float* __restrict__ y,
    const float* __restrict__ u,
    const float* __restrict__ w,
    const float* __restrict__ G,
    float* __restrict__ out)
{
    __shared__ float buf[64][33];

    const int lane = threadIdx.x;
    const int row0 = blockIdx.x * 64;
    const int row  = row0 + lane;
    const int cbase = blockIdx.y * CPB;

    // regressor: 16 y taps + c = u.w_u + w_b
    float r[RDIM];
#pragma unroll
    for (int k = 0; k < AR; ++k) r[k] = y[row * AR + k];
    float c = w[AR + UD];
#pragma unroll
    for (int j = 0; j < UD; ++j) c = fmaf(u[row * UD + j], w[AR + j], c);
    r[16] = c;

    const int half = lane >> 5;
    const int cc   = lane & 31;

    for (int ch = 0; ch < CPB / 32; ++ch) {
        const int tb = cbase + ch * 32;
#pragma unroll
        for (int j = 0; j < 32; ++j) {
            const int t = tb + j;
            float a0 = 0.0f, a1 = 0.0f;
#pragma unroll
            for (int i = 0; i < 8; ++i)      a0 = fmaf(r[i], G[t * RDIM + i], a0);
#pragma unroll
            for (int i = 8; i < RDIM; ++i)   a1 = fmaf(r[i], G[t * RDIM + i], a1);
            buf[lane][j] = a0 + a1;
        }
        __syncthreads();
#pragma unroll
        for (int k = 0; k < 32; ++k) {
            out[(size_t)(row0 + 2 * k + half) * SEQ + tb + cc] = buf[2 * k + half][cc];
        }
        __syncthreads();
    }
}

extern "C" void kernel_launch(void* const* d_in, const int* in_sizes, int n_in,
                              void* d_out, int out_size, void* d_ws, size_t ws_size,
                              hipStream_t stream) {
    const float* y = (const float*)d_in[0];
    const float* u = (const float*)d_in[1];
    const float* w = (const float*)d_in[2];
    float* out = (float*)d_out;
    float* G   = (float*)d_ws;            // SEQ*RDIM*4 = 69,632 B

    gamma_kernel<<<dim3(1), dim3(64), 0, stream>>>(w, G);
    arx_gemm_kernel<<<dim3(BATCH / 64, SEQ / CPB), dim3(64), 0, stream>>>(y, u, w, G, out);
}